// Round 1
// baseline (827.176 us; speedup 1.0000x reference)
//
#include <hip/hip_runtime.h>
#include <hip/hip_bf16.h>

// Problem constants (match reference)
#define T_LEN 4096
#define B_SZ  64
#define C_CH  512
#define W_WORDS 256
#define C4 (C_CH / 4)          // 128 float4 per row
#define TOTAL4 (T_LEN * B_SZ * C4)  // 33,554,432 float4 elements

// Kernel 1: per-batch cumsum of durations + scatter word index into a
// [T, B] int map stored in workspace. widmap[t*B + b] = word index j for
// times covered by word j, or -1 where t >= total duration.
__global__ void build_widmap_kernel(const int* __restrict__ dur,
                                    int* __restrict__ widmap) {
    const int b = blockIdx.x;       // batch
    const int j = threadIdx.x;      // word index, 256 threads == W_WORDS

    __shared__ int s[W_WORDS];
    const int d = dur[b * W_WORDS + j];
    s[j] = d;
    __syncthreads();

    // Hillis-Steele inclusive scan over 256 elements
    #pragma unroll
    for (int off = 1; off < W_WORDS; off <<= 1) {
        int v = (j >= off) ? s[j - off] : 0;
        __syncthreads();
        s[j] += v;
        __syncthreads();
    }
    const int cum = s[j];
    const int start = cum - d;

    // Initialize this batch's column of widmap to -1 (invalid / past total)
    for (int t = j; t < T_LEN; t += W_WORDS)
        widmap[t * B_SZ + b] = -1;
    __syncthreads();

    // Scatter: word j owns times [start, start+d)
    for (int k = 0; k < d; k++)
        widmap[(start + k) * B_SZ + b] = j;
}

// Kernel 2: out = x + pe[wid] (vectorized float4). One float4 per thread.
// C4 = 128, wave = 64 -> every wave shares a single (t,b): wid load is a
// broadcast and the branch is wave-uniform.
__global__ void add_pe_kernel(const float4* __restrict__ x,
                              const float4* __restrict__ pe,
                              const int* __restrict__ widmap,
                              float4* __restrict__ out) {
    const int idx = blockIdx.x * blockDim.x + threadIdx.x;
    if (idx >= TOTAL4) return;
    const int c4 = idx & (C4 - 1);
    const int tb = idx >> 7;        // log2(C4) = 7

    float4 v = x[idx];
    const int wid = widmap[tb];
    if (wid >= 0) {
        const float4 p = pe[wid * C4 + c4];
        v.x += p.x; v.y += p.y; v.z += p.z; v.w += p.w;
    }
    out[idx] = v;
}

extern "C" void kernel_launch(void* const* d_in, const int* in_sizes, int n_in,
                              void* d_out, int out_size, void* d_ws, size_t ws_size,
                              hipStream_t stream) {
    const float* x   = (const float*)d_in[0];        // [T, B, C] fp32
    const float* pe  = (const float*)d_in[1];        // [MAX_LEN, C] fp32
    const int*   dur = (const int*)d_in[2];          // [B, W] int32
    // d_in[3] = train (static 1) — ignored

    float* out = (float*)d_out;                      // [T, B, C] fp32
    int*   widmap = (int*)d_ws;                      // [T, B] int32, 1 MiB

    // Kernel 1: tiny — builds the word-id map
    build_widmap_kernel<<<B_SZ, W_WORDS, 0, stream>>>(dur, widmap);

    // Kernel 2: the memory-bound add
    const int threads = 256;
    const int blocks = TOTAL4 / threads;             // 131072
    add_pe_kernel<<<blocks, threads, 0, stream>>>(
        (const float4*)x, (const float4*)pe, widmap, (float4*)out);
}